// Round 1
// baseline (327.387 us; speedup 1.0000x reference)
//
#include <hip/hip_runtime.h>
#include <stdint.h>
#include <math.h>

// ===========================================================================
// LegacySpikeGeneratorBinomial — exact JAX threefry2x32 replication.
//
// Assumptions (round 1):
//  * jax_threefry_partitionable = True (JAX >= 0.4.30 default):
//      - split is "foldlike": kn = block(folded,(0,0)), ku = block(folded,(0,1))
//      - random_bits(32): bits[j] = hi^lo of block(key, (0, j)) (j < 2^32)
//  * XLA erf_inv f32 = Giles polynomial, w = -log1p(-x*x),
//    log1p small-path threshold 1e-4, log via correctly-rounded double.
//  * All f32 ops individually rounded (fp contract off) to match XLA HLO.
// ===========================================================================

#define TF_R(r) { x0 += x1; x1 = (x1 << (r)) | (x1 >> (32 - (r))); x1 ^= x0; }

static __host__ __device__ inline void tf2x32(uint32_t k0, uint32_t k1,
                                              uint32_t x0, uint32_t x1,
                                              uint32_t& o0, uint32_t& o1) {
  const uint32_t ks2 = k0 ^ k1 ^ 0x1BD11BDAu;
  x0 += k0; x1 += k1;
  TF_R(13) TF_R(15) TF_R(26) TF_R(6)
  x0 += k1; x1 += ks2 + 1u;
  TF_R(17) TF_R(29) TF_R(16) TF_R(24)
  x0 += ks2; x1 += k0 + 2u;
  TF_R(13) TF_R(15) TF_R(26) TF_R(6)
  x0 += k0; x1 += k1 + 3u;
  TF_R(17) TF_R(29) TF_R(16) TF_R(24)
  x0 += k1; x1 += ks2 + 4u;
  TF_R(13) TF_R(15) TF_R(26) TF_R(6)
  x0 += ks2; x1 += k0 + 5u;
  o0 = x0; o1 = x1;
}

// XLA erf_inv expansion for f32 (chlo legalization / math.cc ErfInv32).
__device__ __forceinline__ float erfinv_xla_f32(float x) {
#pragma clang fp contract(off)
  const float xx = x * x;
  const float v = -xx;                       // log1p argument, v in (-1, 0]
  float l1p;
  if (fabsf(v) < 1e-4f) {
    // XLA EmitLog1p small-x path: (-0.5*x + 1) * x
    l1p = (-0.5f * v + 1.0f) * v;
  } else {
    const float arg = v + 1.0f;              // f32-round first, like FAdd(x,1)
    l1p = (float)log((double)arg);           // ~correctly-rounded f32 log
  }
  const float w = -l1p;
  float pp;
  if (w < 5.0f) {
    const float ww = w - 2.5f;
    pp = 2.81022636e-08f;
    pp = 3.43273939e-07f  + pp * ww;
    pp = -3.5233877e-06f  + pp * ww;
    pp = -4.39150654e-06f + pp * ww;
    pp = 0.00021858087f   + pp * ww;
    pp = -0.00125372503f  + pp * ww;
    pp = -0.00417768164f  + pp * ww;
    pp = 0.246640727f     + pp * ww;
    pp = 1.50140941f      + pp * ww;
  } else {
    const float ww = sqrtf(w) - 3.0f;        // sqrtf is IEEE-CR on gfx950
    pp = -0.000200214257f;
    pp = 0.000100950558f  + pp * ww;
    pp = 0.00134934322f   + pp * ww;
    pp = -0.00367342844f  + pp * ww;
    pp = 0.00573950773f   + pp * ww;
    pp = -0.0076224613f   + pp * ww;
    pp = 0.00943887047f   + pp * ww;
    pp = 1.00167406f      + pp * ww;
    pp = 2.83297682f      + pp * ww;
  }
  return pp * x;
}

struct Keys {
  uint32_t kn0[2], ku0[2], kn1[2], ku1[2];   // per-step noise/uniform keys
};

__global__ __launch_bounds__(256) void spike_kernel(
    const float* __restrict__ rates, float* __restrict__ out,
    Keys K, int n) {
#pragma clang fp contract(off)
  const int o = blockIdx.x * 256 + threadIdx.x;
  if (o >= n) return;

  const float p = rates[o] * 1e-4f;          // f32(1/10000) mul, rounded
  int count = 0;

#pragma unroll
  for (int i = 0; i < 2; ++i) {
    const uint32_t knk0 = (i == 0) ? K.kn0[0] : K.kn1[0];
    const uint32_t knk1 = (i == 0) ? K.kn0[1] : K.kn1[1];
    const uint32_t kuk0 = (i == 0) ? K.ku0[0] : K.ku1[0];
    const uint32_t kuk1 = (i == 0) ? K.ku0[1] : K.ku1[1];
#pragma unroll
    for (int s = 0; s < 5; ++s) {
      const uint32_t j = (uint32_t)o + (uint32_t)s * (uint32_t)n;

      // uniform threshold u in [0,1): bits = hi^lo of block(ku, (0,j))
      uint32_t b1, b2;
      tf2x32(kuk0, kuk1, 0u, j, b1, b2);
      const uint32_t ub = b1 ^ b2;
      const float u = __uint_as_float((ub >> 9) | 0x3f800000u) - 1.0f;

      const float diff = u - p;
      // |noise| <= 0.001*sqrt(2)*erfinv(0.9999998..) < 0.0055 — decide
      // without the noise draw when the wave has no borderline lane.
      const bool borderline = fabsf(diff) < 0.006f;
      bool spike;
      if (__any(borderline)) {
        uint32_t n1, n2;
        tf2x32(knk0, knk1, 0u, j, n1, n2);
        const uint32_t nb = n1 ^ n2;
        const float f = __uint_as_float((nb >> 9) | 0x3f800000u) - 1.0f;
        // uniform(lo=-0x1.fffffep-1, hi=1): (hi-lo) folds to exactly 2.0f
        const float un = f * 2.0f + (-0x1.fffffep-1f);
        // lax.max(lo, un) is a no-op: f*2 >= 0 so un >= lo exactly
        const float z = erfinv_xla_f32(un);
        const float nrm = 0x1.6a09e6p+0f * z;   // f32(sqrt(2)) * erfinv
        const float noise = 1e-3f * nrm;        // P_NOISE_STDDEV * normal
        const float t = (p + noise) - u;        // Add then Sub, no FMA
        spike = t > 0.0f;                       // max(sign(t),0): t>0 -> 1
      } else {
        spike = diff < 0.0f;                    // u < p
      }
      count += spike ? 1 : 0;
    }
  }
  out[o] = (float)count;
}

extern "C" void kernel_launch(void* const* d_in, const int* in_sizes, int n_in,
                              void* d_out, int out_size, void* d_ws, size_t ws_size,
                              hipStream_t stream) {
  (void)in_sizes; (void)n_in; (void)d_ws; (void)ws_size;
  const float* rates = (const float*)d_in[0];
  float* out = (float*)d_out;
  const int n = out_size;                      // 8*50*10000*2 = 8,000,000

  // Host-side key derivation (pure arithmetic, graph-capture safe).
  // base key = (0, 42) from jax.random.key(42)
  Keys K;
  for (int i = 0; i < 2; ++i) {
    uint32_t f0, f1;
    tf2x32(0u, 42u, 0u, (uint32_t)i, f0, f1);  // fold_in(key, i)
    uint32_t a0, a1, c0, c1;
    tf2x32(f0, f1, 0u, 0u, a0, a1);            // split -> kn (foldlike)
    tf2x32(f0, f1, 0u, 1u, c0, c1);            // split -> ku
    if (i == 0) { K.kn0[0]=a0; K.kn0[1]=a1; K.ku0[0]=c0; K.ku0[1]=c1; }
    else        { K.kn1[0]=a0; K.kn1[1]=a1; K.ku1[0]=c0; K.ku1[1]=c1; }
  }

  const int grid = (n + 255) / 256;
  hipLaunchKernelGGL(spike_kernel, dim3(grid), dim3(256), 0, stream,
                     rates, out, K, n);
}

// Round 2
// 228.187 us; speedup vs baseline: 1.4347x; 1.4347x over previous
//
#include <hip/hip_runtime.h>
#include <stdint.h>
#include <math.h>

// ===========================================================================
// LegacySpikeGeneratorBinomial — exact JAX threefry2x32 replication.
// Round 2: replace the double-precision log in the noise path with a
// hardware v_log_f32 fast path + rigorous error-interval test; fall back to
// the exact double-log chain only when the decision is within the error band
// (~1e-7 probability per borderline lane). Bit-exact by construction.
// ===========================================================================

#define TF_R(r) { x0 += x1; x1 = (x1 << (r)) | (x1 >> (32 - (r))); x1 ^= x0; }

static __host__ __device__ __forceinline__ void tf2x32(
    uint32_t k0, uint32_t k1, uint32_t x0, uint32_t x1,
    uint32_t& o0, uint32_t& o1) {
  const uint32_t ks2 = k0 ^ k1 ^ 0x1BD11BDAu;
  x0 += k0; x1 += k1;
  TF_R(13) TF_R(15) TF_R(26) TF_R(6)
  x0 += k1; x1 += ks2 + 1u;
  TF_R(17) TF_R(29) TF_R(16) TF_R(24)
  x0 += ks2; x1 += k0 + 2u;
  TF_R(13) TF_R(15) TF_R(26) TF_R(6)
  x0 += k0; x1 += k1 + 3u;
  TF_R(17) TF_R(29) TF_R(16) TF_R(24)
  x0 += k1; x1 += ks2 + 4u;
  TF_R(13) TF_R(15) TF_R(26) TF_R(6)
  x0 += ks2; x1 += k0 + 5u;
  o0 = x0; o1 = x1;
}

#if defined(__HIP_DEVICE_COMPILE__) && __has_builtin(__builtin_amdgcn_logf)
#define FAST_LOG2(x) __builtin_amdgcn_logf(x)   // v_log_f32: log2, <=1 ulp
#else
#define FAST_LOG2(x) __log2f(x)
#endif

// XLA erf_inv f32 Giles polynomial, given w = -log1p(-x*x).
__device__ __forceinline__ float erfinv_poly(float w, float x) {
#pragma clang fp contract(off)
  float pp;
  if (w < 5.0f) {
    const float ww = w - 2.5f;
    pp = 2.81022636e-08f;
    pp = 3.43273939e-07f  + pp * ww;
    pp = -3.5233877e-06f  + pp * ww;
    pp = -4.39150654e-06f + pp * ww;
    pp = 0.00021858087f   + pp * ww;
    pp = -0.00125372503f  + pp * ww;
    pp = -0.00417768164f  + pp * ww;
    pp = 0.246640727f     + pp * ww;
    pp = 1.50140941f      + pp * ww;
  } else {
    const float ww = sqrtf(w) - 3.0f;
    pp = -0.000200214257f;
    pp = 0.000100950558f  + pp * ww;
    pp = 0.00134934322f   + pp * ww;
    pp = -0.00367342844f  + pp * ww;
    pp = 0.00573950773f   + pp * ww;
    pp = -0.0076224613f   + pp * ww;
    pp = 0.00943887047f   + pp * ww;
    pp = 1.00167406f      + pp * ww;
    pp = 2.83297682f      + pp * ww;
  }
  return pp * x;
}

struct Keys {
  uint32_t kn0[2], ku0[2], kn1[2], ku1[2];   // per-step noise/uniform keys
};

__global__ __launch_bounds__(256) void spike_kernel(
    const float* __restrict__ rates, float* __restrict__ out,
    Keys K, int n) {
#pragma clang fp contract(off)
  const int o = blockIdx.x * 256 + threadIdx.x;
  if (o >= n) return;

  const float p = rates[o] * 1e-4f;          // f32(1/10000) mul, rounded
  int count = 0;

#pragma unroll
  for (int i = 0; i < 2; ++i) {
    const uint32_t knk0 = (i == 0) ? K.kn0[0] : K.kn1[0];
    const uint32_t knk1 = (i == 0) ? K.kn0[1] : K.kn1[1];
    const uint32_t kuk0 = (i == 0) ? K.ku0[0] : K.ku1[0];
    const uint32_t kuk1 = (i == 0) ? K.ku0[1] : K.ku1[1];
#pragma unroll
    for (int s = 0; s < 5; ++s) {
      const uint32_t j = (uint32_t)o + (uint32_t)s * (uint32_t)n;

      // uniform threshold u in [0,1): bits = hi^lo of block(ku, (0,j))
      uint32_t b1, b2;
      tf2x32(kuk0, kuk1, 0u, j, b1, b2);
      const uint32_t ub = b1 ^ b2;
      const float u = __uint_as_float((ub >> 9) | 0x3f800000u) - 1.0f;

      const float diff = u - p;
      bool spike = diff < 0.0f;              // decided when |diff| >= max|noise|

      // max |noise| = 1e-3*sqrt(2)*erfinv(0.99999988) = 0.005299 < 0.0054
      if (fabsf(diff) < 0.0054f) {           // divergent; skipped if no lane
        uint32_t n1, n2;
        tf2x32(knk0, knk1, 0u, j, n1, n2);
        const uint32_t nb = n1 ^ n2;
        const float f = __uint_as_float((nb >> 9) | 0x3f800000u) - 1.0f;
        // uniform(lo=-0x1.fffffep-1, hi=1): (hi-lo) folds to exactly 2.0f
        const float x = f * 2.0f + (-0x1.fffffep-1f);
        const float xx = x * x;
        const float v = -xx;                 // log1p argument, in (-1, 0]

        float w;                             // fast w = -log1p(v)
        const bool taylor = fabsf(v) < 1e-4f;
        if (taylor) {
          const float l1p = (-0.5f * v + 1.0f) * v;  // XLA small-x path (exact)
          w = -l1p;
        } else {
          const float arg = v + 1.0f;        // f32-round first, like FAdd
          const float l2 = FAST_LOG2(arg);   // hw log2, <=1 ulp
          w = l2 * -0.69314718055994530942f; // -> -log(arg), err <= 2.4e-7*w
        }

        const float z = erfinv_poly(w, x);
        // |z_fast - z_exact| <= Lip*dw + 2*poly_round <= ~2e-6; margin 15x:
        const float DZ = 3e-5f;
        const float nlo = 1e-3f * (0x1.6a09e6p+0f * (z - DZ));
        const float nhi = 1e-3f * (0x1.6a09e6p+0f * (z + DZ));
        const float tlo = (p + nlo) - u;     // same rounded chain as exact
        const float thi = (p + nhi) - u;     // (monotone in z)
        const bool slo = tlo > 0.0f;
        const bool shi = thi > 0.0f;
        const bool risky = (!taylor) && (fabsf(w - 5.0f) < 1e-3f);

        if (slo == shi && !risky) {
          spike = slo;
        } else {
          // exact chain (prob ~1e-7 per borderline lane): CR f32 log
          float we;
          if (taylor) {
            we = w;                          // Taylor path is already exact
          } else {
            const float arg = v + 1.0f;
            we = -(float)log((double)arg);
          }
          const float ze = erfinv_poly(we, x);
          const float nz = 1e-3f * (0x1.6a09e6p+0f * ze);
          const float t = (p + nz) - u;      // Add then Sub, no FMA
          spike = t > 0.0f;                  // max(sign(t),0): t>0 -> 1
        }
      }
      count += spike ? 1 : 0;
    }
  }
  out[o] = (float)count;
}

extern "C" void kernel_launch(void* const* d_in, const int* in_sizes, int n_in,
                              void* d_out, int out_size, void* d_ws, size_t ws_size,
                              hipStream_t stream) {
  (void)in_sizes; (void)n_in; (void)d_ws; (void)ws_size;
  const float* rates = (const float*)d_in[0];
  float* out = (float*)d_out;
  const int n = out_size;                      // 8*50*10000*2 = 8,000,000

  // Host-side key derivation (pure arithmetic, graph-capture safe).
  // base key = (0, 42) from jax.random.key(42)
  Keys K;
  for (int i = 0; i < 2; ++i) {
    uint32_t f0, f1;
    tf2x32(0u, 42u, 0u, (uint32_t)i, f0, f1);  // fold_in(key, i)
    uint32_t a0, a1, c0, c1;
    tf2x32(f0, f1, 0u, 0u, a0, a1);            // split -> kn (foldlike)
    tf2x32(f0, f1, 0u, 1u, c0, c1);            // split -> ku
    if (i == 0) { K.kn0[0]=a0; K.kn0[1]=a1; K.ku0[0]=c0; K.ku0[1]=c1; }
    else        { K.kn1[0]=a0; K.kn1[1]=a1; K.ku1[0]=c0; K.ku1[1]=c1; }
  }

  const int grid = (n + 255) / 256;
  hipLaunchKernelGGL(spike_kernel, dim3(grid), dim3(256), 0, stream,
                     rates, out, K, n);
}

// Round 3
// 164.881 us; speedup vs baseline: 1.9856x; 1.3839x over previous
//
#include <hip/hip_runtime.h>
#include <stdint.h>
#include <math.h>

// ===========================================================================
// LegacySpikeGeneratorBinomial — exact JAX threefry2x32 replication.
// Round 3: block-level compaction of borderline draws. The main loop does
// only the mandatory uniform threefry per draw; borderline lanes (~1.1%)
// push (u, owner, draw) into an LDS queue. One batch pass after the loop
// resolves them with the exact erfinv chain and applies +-1 corrections via
// LDS atomics (commutative -> deterministic). Threefry rotates forced to
// v_alignbit_b32 via __builtin_rotateleft32.
// ===========================================================================

#if __has_builtin(__builtin_rotateleft32)
#define ROTL32(x, r) __builtin_rotateleft32((x), (r))
#else
#define ROTL32(x, r) (((x) << (r)) | ((x) >> (32 - (r))))
#endif

#define TF_R(r) { x0 += x1; x1 = ROTL32(x1, (r)); x1 ^= x0; }

static __host__ __device__ __forceinline__ void tf2x32(
    uint32_t k0, uint32_t k1, uint32_t x0, uint32_t x1,
    uint32_t& o0, uint32_t& o1) {
  const uint32_t ks2 = k0 ^ k1 ^ 0x1BD11BDAu;
  x0 += k0; x1 += k1;
  TF_R(13) TF_R(15) TF_R(26) TF_R(6)
  x0 += k1; x1 += ks2 + 1u;
  TF_R(17) TF_R(29) TF_R(16) TF_R(24)
  x0 += ks2; x1 += k0 + 2u;
  TF_R(13) TF_R(15) TF_R(26) TF_R(6)
  x0 += k0; x1 += k1 + 3u;
  TF_R(17) TF_R(29) TF_R(16) TF_R(24)
  x0 += k1; x1 += ks2 + 4u;
  TF_R(13) TF_R(15) TF_R(26) TF_R(6)
  x0 += ks2; x1 += k0 + 5u;
  o0 = x0; o1 = x1;
}

// XLA erf_inv f32 Giles polynomial, given w = -log1p(-x*x).
__device__ __forceinline__ float erfinv_poly(float w, float x) {
#pragma clang fp contract(off)
  float pp;
  if (w < 5.0f) {
    const float ww = w - 2.5f;
    pp = 2.81022636e-08f;
    pp = 3.43273939e-07f  + pp * ww;
    pp = -3.5233877e-06f  + pp * ww;
    pp = -4.39150654e-06f + pp * ww;
    pp = 0.00021858087f   + pp * ww;
    pp = -0.00125372503f  + pp * ww;
    pp = -0.00417768164f  + pp * ww;
    pp = 0.246640727f     + pp * ww;
    pp = 1.50140941f      + pp * ww;
  } else {
    const float ww = sqrtf(w) - 3.0f;
    pp = -0.000200214257f;
    pp = 0.000100950558f  + pp * ww;
    pp = 0.00134934322f   + pp * ww;
    pp = -0.00367342844f  + pp * ww;
    pp = 0.00573950773f   + pp * ww;
    pp = -0.0076224613f   + pp * ww;
    pp = 0.00943887047f   + pp * ww;
    pp = 1.00167406f      + pp * ww;
    pp = 2.83297682f      + pp * ww;
  }
  return pp * x;
}

struct Keys {
  uint32_t kn0[2], ku0[2], kn1[2], ku1[2];   // per-step noise/uniform keys
};

// Exact XLA chain: noise draw at counter j with key (k0,k1), decide spike.
__device__ __forceinline__ int noise_spike_exact(
    uint32_t k0, uint32_t k1, uint32_t j, float p, float u) {
#pragma clang fp contract(off)
  uint32_t n1, n2;
  tf2x32(k0, k1, 0u, j, n1, n2);
  const uint32_t nb = n1 ^ n2;
  const float f = __uint_as_float((nb >> 9) | 0x3f800000u) - 1.0f;
  // uniform(lo=-0x1.fffffep-1, hi=1): (hi-lo) folds to exactly 2.0f;
  // lax.max(lo, .) is a no-op since f*2 >= 0.
  const float x = f * 2.0f + (-0x1.fffffep-1f);
  const float xx = x * x;
  const float v = -xx;                       // log1p argument, in (-1, 0]
  float we;
  if (fabsf(v) < 1e-4f) {
    we = -((-0.5f * v + 1.0f) * v);          // XLA EmitLog1p small path
  } else {
    const float arg = v + 1.0f;              // f32-round first (FAdd)
    we = -(float)log((double)arg);           // ~CR f32 log
  }
  const float ze = erfinv_poly(we, x);
  const float nz = 1e-3f * (0x1.6a09e6p+0f * ze);  // stddev * sqrt2 * erfinv
  const float t = (p + nz) - u;              // Add then Sub, no FMA
  return t > 0.0f ? 1 : 0;                   // max(sign(t),0)
}

#define CAP 512

__global__ __launch_bounds__(256) void spike_kernel(
    const float* __restrict__ rates, float* __restrict__ out,
    Keys K, int n) {
#pragma clang fp contract(off)
  __shared__ int s_cnt;
  __shared__ float s_u[CAP];
  __shared__ uint32_t s_owner[CAP];          // (tid << 4) | draw_id
  __shared__ int s_delta[256];

  const int tid = threadIdx.x;
  const int o = blockIdx.x * 256 + tid;

  s_delta[tid] = 0;
  if (tid == 0) s_cnt = 0;
  __syncthreads();

  const float p = (o < n) ? rates[o] * 1e-4f : 0.0f;
  int count = 0;

  if (o < n) {
#pragma unroll
    for (int i = 0; i < 2; ++i) {
      const uint32_t kuk0 = (i == 0) ? K.ku0[0] : K.ku1[0];
      const uint32_t kuk1 = (i == 0) ? K.ku0[1] : K.ku1[1];
#pragma unroll
      for (int s = 0; s < 5; ++s) {
        const int d = i * 5 + s;             // draw id 0..9
        const uint32_t j = (uint32_t)o + (uint32_t)s * (uint32_t)n;

        // uniform threshold u in [0,1): bits = hi^lo of block(ku, (0,j))
        uint32_t b1, b2;
        tf2x32(kuk0, kuk1, 0u, j, b1, b2);
        const uint32_t ub = b1 ^ b2;
        const float u = __uint_as_float((ub >> 9) | 0x3f800000u) - 1.0f;

        const float diff = u - p;
        const int spike0 = (diff < 0.0f) ? 1 : 0;
        count += spike0;

        // max |noise| = 1e-3*sqrt(2)*erfinv(0.99999988) = 0.005299 < 0.0054
        if (fabsf(diff) < 0.0054f) {
          const int slot = atomicAdd(&s_cnt, 1);
          if (slot < CAP) {
            s_u[slot] = u;
            s_owner[slot] = ((uint32_t)tid << 4) | (uint32_t)d;
          } else {
            // overflow fallback (statistically unreachable): exact inline
            const uint32_t k0 = (i == 0) ? K.kn0[0] : K.kn1[0];
            const uint32_t k1 = (i == 0) ? K.kn0[1] : K.kn1[1];
            count += noise_spike_exact(k0, k1, j, p, u) - spike0;
          }
        }
      }
    }
  }

  __syncthreads();
  const int cnt = min(s_cnt, CAP);

  // Batch-resolve borderline draws (expected ~28 per block -> 1 partial wave)
  for (int base = 0; base < cnt; base += 256) {
    const int idx = base + tid;
    if (idx < cnt) {
      const uint32_t ow = s_owner[idx];
      const int otid = (int)(ow >> 4);
      const int d = (int)(ow & 15u);
      const int i = d >= 5 ? 1 : 0;
      const int s = d - i * 5;
      const int oo = blockIdx.x * 256 + otid;
      const float po = rates[oo] * 1e-4f;    // same rounding as main loop
      const float u = s_u[idx];
      const uint32_t j = (uint32_t)oo + (uint32_t)s * (uint32_t)n;
      const uint32_t k0 = (i == 0) ? K.kn0[0] : K.kn1[0];
      const uint32_t k1 = (i == 0) ? K.kn0[1] : K.kn1[1];
      const int spike = noise_spike_exact(k0, k1, j, po, u);
      const int spike0 = ((u - po) < 0.0f) ? 1 : 0;
      const int delta = spike - spike0;
      if (delta != 0) atomicAdd(&s_delta[otid], delta);
    }
  }

  __syncthreads();
  if (o < n) out[o] = (float)(count + s_delta[tid]);
}

extern "C" void kernel_launch(void* const* d_in, const int* in_sizes, int n_in,
                              void* d_out, int out_size, void* d_ws, size_t ws_size,
                              hipStream_t stream) {
  (void)in_sizes; (void)n_in; (void)d_ws; (void)ws_size;
  const float* rates = (const float*)d_in[0];
  float* out = (float*)d_out;
  const int n = out_size;                      // 8*50*10000*2 = 8,000,000

  // Host-side key derivation (pure arithmetic, graph-capture safe).
  // base key = (0, 42) from jax.random.key(42)
  Keys K;
  for (int i = 0; i < 2; ++i) {
    uint32_t f0, f1;
    tf2x32(0u, 42u, 0u, (uint32_t)i, f0, f1);  // fold_in(key, i)
    uint32_t a0, a1, c0, c1;
    tf2x32(f0, f1, 0u, 0u, a0, a1);            // split -> kn (foldlike)
    tf2x32(f0, f1, 0u, 1u, c0, c1);            // split -> ku
    if (i == 0) { K.kn0[0]=a0; K.kn0[1]=a1; K.ku0[0]=c0; K.ku0[1]=c1; }
    else        { K.kn1[0]=a0; K.kn1[1]=a1; K.ku1[0]=c0; K.ku1[1]=c1; }
  }

  const int grid = (n + 255) / 256;
  hipLaunchKernelGGL(spike_kernel, dim3(grid), dim3(256), 0, stream,
                     rates, out, K, n);
}